// Round 1
// baseline (9.705 us; speedup 1.0000x reference)
//
#include <hip/hip_runtime.h>

#define BATCH 16384

__global__ __launch_bounds__(64) void neumf_kernel(
    const int*   __restrict__ user_ids,
    const int*   __restrict__ movie_ids,
    const float* __restrict__ gmf_user,   // [NU, 64]
    const float* __restrict__ gmf_movie,  // [NM, 64]
    const float* __restrict__ mlp_user,   // [NU, 8]
    const float* __restrict__ mlp_movie,  // [NM, 8]
    const float* __restrict__ W1,         // [16, 8]
    const float* __restrict__ b1,         // [8]
    const float* __restrict__ W2,         // [8, 4]
    const float* __restrict__ b2,         // [4]
    const float* __restrict__ Wf,         // [68, 1]
    const float* __restrict__ bf,         // [1]
    float*       __restrict__ out)        // [BATCH]
{
    int i = blockIdx.x * blockDim.x + threadIdx.x;
    if (i >= BATCH) return;

    const int uid = user_ids[i];
    const int mid = movie_ids[i];

    const float4* u4 = (const float4*)(gmf_user  + (size_t)uid * 64);
    const float4* m4 = (const float4*)(gmf_movie + (size_t)mid * 64);
    const float4* w4 = (const float4*)Wf;   // first 64 entries, uniform -> s_load

    // GMF branch fused with final dot: sum_k u[k]*m[k]*Wf[k]
    float acc = 0.f;
    #pragma unroll
    for (int j = 0; j < 16; ++j) {
        float4 a = u4[j];
        float4 b = m4[j];
        float4 w = w4[j];
        acc += a.x * b.x * w.x;
        acc += a.y * b.y * w.y;
        acc += a.z * b.z * w.z;
        acc += a.w * b.w * w.w;
    }

    // MLP input: concat(mlp_user[uid], mlp_movie[mid]) -> 16
    float in16[16];
    {
        const float4* mu = (const float4*)(mlp_user  + (size_t)uid * 8);
        const float4* mm = (const float4*)(mlp_movie + (size_t)mid * 8);
        float4 t;
        t = mu[0]; in16[0]  = t.x; in16[1]  = t.y; in16[2]  = t.z; in16[3]  = t.w;
        t = mu[1]; in16[4]  = t.x; in16[5]  = t.y; in16[6]  = t.z; in16[7]  = t.w;
        t = mm[0]; in16[8]  = t.x; in16[9]  = t.y; in16[10] = t.z; in16[11] = t.w;
        t = mm[1]; in16[12] = t.x; in16[13] = t.y; in16[14] = t.z; in16[15] = t.w;
    }

    // h1 = relu(in16 @ W1 + b1)   [16x8]
    float h1[8];
    #pragma unroll
    for (int j = 0; j < 8; ++j) {
        float s = b1[j];
        #pragma unroll
        for (int k = 0; k < 16; ++k) s = fmaf(in16[k], W1[k * 8 + j], s);
        h1[j] = fmaxf(s, 0.f);
    }

    // h2 = relu(h1 @ W2 + b2)     [8x4], fused with final dot Wf[64..67]
    #pragma unroll
    for (int j = 0; j < 4; ++j) {
        float s = b2[j];
        #pragma unroll
        for (int k = 0; k < 8; ++k) s = fmaf(h1[k], W2[k * 4 + j], s);
        s = fmaxf(s, 0.f);
        acc = fmaf(s, Wf[64 + j], acc);
    }

    const float logit = acc + bf[0];
    const float sig = 1.f / (1.f + __expf(-logit));
    out[i] = sig * 4.f + 1.f;
}

extern "C" void kernel_launch(void* const* d_in, const int* in_sizes, int n_in,
                              void* d_out, int out_size, void* d_ws, size_t ws_size,
                              hipStream_t stream) {
    const int*   user_ids  = (const int*)  d_in[0];
    const int*   movie_ids = (const int*)  d_in[1];
    const float* gmf_user  = (const float*)d_in[2];
    const float* gmf_movie = (const float*)d_in[3];
    const float* mlp_user  = (const float*)d_in[4];
    const float* mlp_movie = (const float*)d_in[5];
    const float* W1        = (const float*)d_in[6];
    const float* b1        = (const float*)d_in[7];
    const float* W2        = (const float*)d_in[8];
    const float* b2        = (const float*)d_in[9];
    const float* Wf        = (const float*)d_in[10];
    const float* bf        = (const float*)d_in[11];
    float*       out       = (float*)d_out;

    const int threads = 64;                       // one wave per block
    const int blocks  = (BATCH + threads - 1) / threads;  // 256 blocks -> ~1/CU
    neumf_kernel<<<blocks, threads, 0, stream>>>(
        user_ids, movie_ids, gmf_user, gmf_movie, mlp_user, mlp_movie,
        W1, b1, W2, b2, Wf, bf, out);
}